// Round 4
// baseline (154.267 us; speedup 1.0000x reference)
//
#include <hip/hip_runtime.h>
#include <math.h>

#define G_MAX 512   // capacity for GT boxes; setup uses G=300 (requires G <= 511)
#define SPLIT 4     // threads per anchor (window-loop split)

// per-image sorted-GT workspace layout (bytes)
#define IMG_WS_STRIDE 16384
#define OFF_BOX   0        // float4[G_MAX]: x0, y0, x1+1, y1+1 (sorted by x0)
#define OFF_META  8192     // float2[G_MAX]: (area | 1e30 invalid, orig-g bits)
#define OFF_O2S   12288    // ushort[G_MAX]: orig g -> sorted slot (g>=G -> G dummy)
#define OFF_SPAN  13312    // float: max(x1p - x0) + 1 (rounding slack)

__device__ __forceinline__ float waveSum(float v) {
#pragma unroll
  for (int o = 32; o > 0; o >>= 1) v += __shfl_down(v, o, 64);
  return v;
}

// smooth-L1 with sigma=3 (s2=9)
__device__ __forceinline__ float huber9(float x) {
  float ax = fabsf(x);
  return (ax < (1.0f / 9.0f)) ? 4.5f * x * x : ax - (0.5f / 9.0f);
}

// Exact IoU in the reference's op order. g = (x0, y0, x1+1, y1+1)
__device__ __forceinline__ float iouExact(float bx0, float by0, float bx1, float by1,
                                          float areab, float4 g, float areag) {
  float gx1 = g.z - 1.0f, gy1 = g.w - 1.0f;  // exact inverse of staged +1 (coords < 2^24)
  float iw = fminf(bx1, gx1) - fmaxf(bx0, g.x) + 1.0f;
  float ih = fminf(by1, gy1) - fmaxf(by0, g.y) + 1.0f;
  float inter = fmaxf(iw, 0.f) * fmaxf(ih, 0.f);
  float uni = areab + areag - inter;
  return inter / fmaxf(uni, 1.0f);
}

// Inverse comparison key: key = (areaB+areaG)*rcp(inter); argmax iou == argmin
// key (uint compare on positive floats). ONE-CLAMP trick: inter = max(iw,0)*ih.
//   ih >= 0: identical to the two-clamp value (positive-overlap keys exact).
//   ih <  0: key negative/-inf -> uint >= 0x80000000 -> loses under min-tracking.
//   iw <= 0, ih > 0: inter = +0 -> key = +inf -> loses to all finite positives.
// Zero-overlap/invalid internal order is output-invariant (winners recomputed
// exactly with validity masks -> label 0 / fg=false / value 0).
// Low 9 bits carry ORIGINAL g: min-ties resolve to smallest g (jax stable).
__device__ __forceinline__ uint32_t packKey(float x0, float y0, float x1p, float y1p,
                                            float area, float4 gb, float ga,
                                            uint32_t g) {
  float iw = fminf(x1p, gb.z) - fmaxf(x0, gb.x);
  float ih = fminf(y1p, gb.w) - fmaxf(y0, gb.y);
  float inter = fmaxf(iw, 0.f) * ih;
  float key = (area + ga) * __builtin_amdgcn_rcpf(inter);
  return (__float_as_uint(key) & 0xFFFFFE00u) | g;
}

// first s in [0,n) with sBox[s].x >= t
__device__ __forceinline__ int lbX(const float4* sBox, int n, float t) {
  int lo = 0, cnt = n;
  while (cnt > 0) {
    int half = cnt >> 1;
    int mid = lo + half;
    if (sBox[mid].x < t) { lo = mid + 1; cnt -= half + 1; }
    else cnt = half;
  }
  return lo;
}

// ---------------- pre-pass: per-image GT sort by x0 (O(G^2) rank) ----------------
__global__ __launch_bounds__(256) void gt_sort(
    const float* __restrict__ boxes, int G, char* __restrict__ ws) {
  const int img = blockIdx.x;
  const float* gtb = boxes + (size_t)img * G * 5;
  char* wsb = ws + (size_t)img * IMG_WS_STRIDE;
  float4* wBox = (float4*)(wsb + OFF_BOX);
  float2* wMeta = (float2*)(wsb + OFF_META);
  unsigned short* wO2S = (unsigned short*)(wsb + OFF_O2S);
  float* wSpan = (float*)(wsb + OFF_SPAN);

  __shared__ float lx0[G_MAX], ly0[G_MAX], lx1[G_MAX], ly1[G_MAX], llb[G_MAX];
  __shared__ float sMax[256];

  for (int g = threadIdx.x; g < G; g += 256) {
    lx0[g] = gtb[g * 5 + 0]; ly0[g] = gtb[g * 5 + 1];
    lx1[g] = gtb[g * 5 + 2]; ly1[g] = gtb[g * 5 + 3];
    llb[g] = gtb[g * 5 + 4];
  }
  __syncthreads();

  float mspan = 0.f;
  for (int g = threadIdx.x; g < G; g += 256) {
    float x0 = lx0[g];
    int r = 0;
    for (int j = 0; j < G; ++j) {
      float xj = lx0[j];
      r += (xj < x0 || (xj == x0 && j < g)) ? 1 : 0;  // stable rank
    }
    float x1p = lx1[g] + 1.0f, y1p = ly1[g] + 1.0f;
    wBox[r] = make_float4(x0, ly0[g], x1p, y1p);
    float area = (llb[g] != -1.0f)
                     ? (lx1[g] - x0 + 1.0f) * (ly1[g] - ly0[g] + 1.0f)
                     : 1e30f;
    wMeta[r] = make_float2(area, __uint_as_float((unsigned)g));
    wO2S[g] = (unsigned short)r;
    mspan = fmaxf(mspan, x1p - x0);
  }
  // dummy slots [G, G_MAX) + o2s for out-of-range orig indices (sentinel 0x1FF)
  for (int s = G + threadIdx.x; s < G_MAX; s += 256) {
    wBox[s] = make_float4(0.f, 0.f, 1.f, 1.f);
    wMeta[s] = make_float2(1e30f, __uint_as_float((unsigned)s));
    wO2S[s] = (unsigned short)G;  // -> dummy slot (area 1e30 -> invalid path)
  }
  sMax[threadIdx.x] = mspan;
  __syncthreads();
  for (int off = 128; off > 0; off >>= 1) {
    if (threadIdx.x < off) sMax[threadIdx.x] = fmaxf(sMax[threadIdx.x], sMax[threadIdx.x + off]);
    __syncthreads();
  }
  if (threadIdx.x == 0) *wSpan = sMax[0] + 1.0f;  // +1 px float-rounding slack
}

__global__ __launch_bounds__(256) void retina_main(
    const float* __restrict__ pred_cls,   // (n, A, 2)
    const float* __restrict__ rpn_num,    // (n, A, 2)
    const float* __restrict__ pred_reg,   // (n, A, 8)
    const float* __restrict__ anchors,    // (A, 4)
    const float* __restrict__ rpn_iou,    // (n, A, 2)
    int A, int G,
    const char* __restrict__ ws_sorted,   // per-image sorted-GT blocks
    double* __restrict__ partial)         // (nB, 8) doubles, private per block
{
  __shared__ float4 sBox[G_MAX];          // sorted by x0: x0, y0, x1+1, y1+1
  __shared__ float2 sMeta[G_MAX];         // (area | 1e30, orig-g bits)
  __shared__ unsigned short sO2S[G_MAX];  // orig g -> sorted slot
  __shared__ float sRed[4][7];
  __shared__ float sStash[64][10];        // decoded boxes of needy anchors
  __shared__ float2 sRes[64];             // aval/bval results (by quad id)
  __shared__ unsigned char sList[64];     // slot -> quad id
  __shared__ int sNum;

  const int img = blockIdx.y;
  const int seg = threadIdx.x & (SPLIT - 1);
  const int q   = threadIdx.x >> 2;       // quad id 0..63, one anchor each
  const int i   = blockIdx.x * 64 + q;
  const int ic  = (i < A) ? i : (A - 1);

  const char* wsb = ws_sorted + (size_t)img * IMG_WS_STRIDE;
  const float4* wBox = (const float4*)(wsb + OFF_BOX);
  const float2* wMeta = (const float2*)(wsb + OFF_META);
  const unsigned short* wO2S = (const unsigned short*)(wsb + OFF_O2S);
  const float maxSpan = *(const float*)(wsb + OFF_SPAN);

  if (threadIdx.x == 0) sNum = 0;

  // stage sorted GT data (small: ~13 KB, L2-resident source)
  for (int s = threadIdx.x; s < G_MAX; s += 256) {
    sBox[s] = wBox[s];
    sMeta[s] = wMeta[s];
    sO2S[s] = wO2S[s];
  }
  __syncthreads();

  float t_cls = 0.f, t_bbox = 0.f, t_iou = 0.f, t_num = 0.f;
  float t_npos = 0.f, t_nfg = 0.f, t_ncnt = 0.f;

  const float BBOX_CLIP = 4.1351666f;  // log(1000/16)

  // per-anchor data (4 lanes share one anchor; redundant loads hit L1)
  float ax0 = anchors[ic * 4 + 0], ay0 = anchors[ic * 4 + 1];
  float ax1 = anchors[ic * 4 + 2], ay1 = anchors[ic * 4 + 3];
  float aw = ax1 - ax0 + 1.0f, ah = ay1 - ay0 + 1.0f;
  float areaa = aw * ah;
  float acx = ax0 + 0.5f * aw, acy = ay0 + 0.5f * ah;
  float ax1p = ax1 + 1.0f, ay1p = ay1 + 1.0f;

  // epilogue-only inputs: issue early (exec-masked to seg 0) to hide latency
  float d0 = 0.f, d1 = 0.f, d2 = 0.f, d3 = 0.f;
  float d4 = 0.f, d5 = 0.f, d6 = 0.f, d7 = 0.f;
  float pcv0 = 0.f, pcv1 = 0.f, riv0 = 0.f, riv1 = 0.f, sn0 = 0.f, sn1 = 0.f;
  if (seg == 0) {
    const float* dp = pred_reg + ((size_t)img * A + ic) * 8;
    d0 = dp[0]; d1 = dp[1]; d2 = dp[2]; d3 = dp[3];
    d4 = dp[4]; d5 = dp[5]; d6 = dp[6]; d7 = dp[7];
    const float* pc = pred_cls + ((size_t)img * A + ic) * 2;
    pcv0 = pc[0]; pcv1 = pc[1];
    const float* ri = rpn_iou + ((size_t)img * A + ic) * 2;
    riv0 = ri[0]; riv1 = ri[1];
    const float* sp = rpn_num + ((size_t)img * A + ic) * 2;
    sn0 = sp[0]; sn1 = sp[1];
  }

  // ---------------- phase 1: anchor-vs-gt top-2, x-window pruned ----------------
  // Pruned pairs are provably zero-x-overlap (gt.x1p < a.x0 or gt.x0 >= a.x1p)
  // -> zero-overlap class -> output-invariant (see packKey comment).
  uint32_t an1 = 0xFFFFFFFFu, an2 = 0xFFFFFFFFu;
  {
    int lo = lbX(sBox, G, ax0 - maxSpan);
    int hi = lbX(sBox, G, ax1p);
#pragma unroll 2
    for (int s = lo + seg; s < hi; s += SPLIT) {
      float4 gb = sBox[s];
      float2 mt = sMeta[s];
      uint32_t p = packKey(ax0, ay0, ax1p, ay1p, areaa, gb, mt.x,
                           __float_as_uint(mt.y));
      uint32_t h = max(p, an1);
      an1 = min(an1, p);
      an2 = min(an2, h);
    }
  }

  // butterfly merge across the 4 lanes of this quad
#pragma unroll
  for (int m = 1; m <= 2; m <<= 1) {
    uint32_t o1 = (uint32_t)__shfl_xor((int)an1, m, 64);
    uint32_t o2 = (uint32_t)__shfl_xor((int)an2, m, 64);
    uint32_t hi = max(an1, o1);
    an1 = min(an1, o1);
    an2 = min(min(an2, o2), hi);
  }

  bool fg0 = false, fg1 = false, needy = false;

  if (seg == 0 && i < A) {
    // winning ORIGINAL indices -> sorted slots (sentinel 0x1FF -> dummy slot)
    int og0 = (int)(an1 & 0x1FFu);
    int og1 = (int)(an2 & 0x1FFu);
    int s0 = sO2S[og0];
    int s1 = sO2S[og1];

    // exact recompute of winning values (reference op order, explicit validity)
    float4 g0 = sBox[s0]; float a0 = sMeta[s0].x; bool val0 = a0 < 1e29f;
    float v0 = val0 ? iouExact(ax0, ay0, ax1, ay1, areaa, g0, a0) : -1.0f;
    float4 g1 = sBox[s1]; float a1 = sMeta[s1].x; bool val1 = a1 < 1e29f;
    float v1 = val1 ? iouExact(ax0, ay0, ax1, ay1, areaa, g1, a1) : -1.0f;

    // labels: >=0.5 -> 1, <0.4 -> 0, else -1
    float la  = (v0 >= 0.5f) ? 1.0f : ((v0 < 0.4f) ? 0.0f : -1.0f);
    float lbv = (v1 >= 0.5f) ? 1.0f : ((v1 < 0.4f) ? 0.0f : -1.0f);
    float lab0 = la;
    float lab1 = lbv - (((la == 0.0f) && (lbv != 0.0f)) ? 1.0f : 0.0f);

    // ---- focal classification loss ----
    {
      float p = pcv0;
      if (lab0 != -1.0f) {
        float l = (lab0 == 1.0f)
                      ? 0.25f * (1.0f - p) * (1.0f - p) * logf(p)
                      : 0.75f * p * p * logf(1.0f - p);
        t_cls -= l;
      }
      if (lab0 > 0.f) t_npos += 1.f;
      float qv = pcv1;
      if (lab1 != -1.0f) {
        float l = (lab1 == 1.0f)
                      ? 0.25f * (1.0f - qv) * (1.0f - qv) * logf(qv)
                      : 0.75f * qv * qv * logf(1.0f - qv);
        t_cls -= l;
      }
      if (lab1 > 0.f) t_npos += 1.f;
    }

    fg0 = (lab0 != 0.0f) && (lab0 != -1.0f);
    fg1 = (lab1 != 0.0f) && (lab1 != -1.0f);

    // fast reciprocals for the bbox-target divides (rel err ~1e-7, harmless)
    float raw = __builtin_amdgcn_rcpf(aw), rah = __builtin_amdgcn_rcpf(ah);

    // ---- bbox smooth-L1 vs bbox_transform(anchor, matched gt) ----
    if (fg0) {
      float mx1 = g0.z - 1.0f, my1 = g0.w - 1.0f;
      float gw = mx1 - g0.x + 1.0f, gh = my1 - g0.y + 1.0f;
      float gcx = g0.x + 0.5f * gw, gcy = g0.y + 0.5f * gh;
      float t0 = (gcx - acx) * raw, t1v = (gcy - acy) * rah;
      float t2 = logf(gw * raw), t3 = logf(gh * rah);
      t_bbox += huber9(d0 - t0) + huber9(d1 - t1v) + huber9(d2 - t2) + huber9(d3 - t3);
      t_nfg += 1.f;
    }
    if (fg1) {
      float mx1 = g1.z - 1.0f, my1 = g1.w - 1.0f;
      float gw = mx1 - g1.x + 1.0f, gh = my1 - g1.y + 1.0f;
      float gcx = g1.x + 0.5f * gw, gcy = g1.y + 0.5f * gh;
      float t0 = (gcx - acx) * raw, t1v = (gcy - acy) * rah;
      float t2 = logf(gw * raw), t3 = logf(gh * rah);
      t_bbox += huber9(d4 - t0) + huber9(d5 - t1v) + huber9(d6 - t2) + huber9(d7 - t3);
      t_nfg += 1.f;
    }

    // ---- num softmax loss ----
    {
      int nl = ((lab0 > 0.f) ? 1 : 0) + ((lab1 > 0.f) ? 1 : 0) - 1;
      if (nl != -1) {
        float m = fmaxf(sn0, sn1);
        float lse = m + logf(expf(sn0 - m) + expf(sn1 - m));
        float picked = ((nl == 0) ? sn0 : sn1) - lse;
        t_num -= picked;
        t_ncnt += 1.f;
      }
    }

    // ---- enqueue for phase 2 (decoded-box argmaxes) only if fg ----
    needy = fg0 || fg1;
    if (needy) {
      // decode predicted boxes (identical expressions to the original)
      float p0cx = acx + d0 * aw, p0cy = acy + d1 * ah;
      float p0w = aw * expf(fminf(d2, BBOX_CLIP));
      float p0h = ah * expf(fminf(d3, BBOX_CLIP));
      float b0x0 = p0cx - 0.5f * p0w, b0y0 = p0cy - 0.5f * p0h;
      float b0x1 = p0cx + 0.5f * p0w, b0y1 = p0cy + 0.5f * p0h;
      float area0 = (b0x1 - b0x0 + 1.0f) * (b0y1 - b0y0 + 1.0f);

      float p1cx = acx + d4 * aw, p1cy = acy + d5 * ah;
      float p1w = aw * expf(fminf(d6, BBOX_CLIP));
      float p1h = ah * expf(fminf(d7, BBOX_CLIP));
      float b1x0 = p1cx - 0.5f * p1w, b1y0 = p1cy - 0.5f * p1h;
      float b1x1 = p1cx + 0.5f * p1w, b1y1 = p1cy + 0.5f * p1h;
      float area1 = (b1x1 - b1x0 + 1.0f) * (b1y1 - b1y0 + 1.0f);

      int slot = atomicAdd(&sNum, 1);
      sList[slot] = (unsigned char)q;
      float* st = sStash[slot];
      st[0] = b0x0; st[1] = b0y0; st[2] = b0x1; st[3] = b0y1; st[4] = area0;
      st[5] = b1x0; st[6] = b1y0; st[7] = b1x1; st[8] = b1y1; st[9] = area1;
    }
  }
  __syncthreads();

  // ---------------- phase 2: compacted decoded-box argmaxes (windowed) --------
  {
    int num = sNum;
    int slot = threadIdx.x >> 2;
    int wseg = threadIdx.x & 3;
    if (slot < num) {   // uniform across each quad -> shfl butterfly safe
      const float* st = sStash[slot];
      float c0x0 = st[0], c0y0 = st[1], c0x1 = st[2], c0y1 = st[3], car0 = st[4];
      float c1x0 = st[5], c1y0 = st[6], c1x1 = st[7], c1y1 = st[8], car1 = st[9];
      float c0x1p = c0x1 + 1.0f, c0y1p = c0y1 + 1.0f;
      float c1x1p = c1x1 + 1.0f, c1y1p = c1y1 + 1.0f;

      uint32_t am = 0xFFFFFFFFu;                     // box 0 best
      uint32_t bk1 = 0xFFFFFFFFu, bk2 = 0xFFFFFFFFu; // box 1 best/2nd

      // union window covering both decoded boxes (extra GTs are zero-overlap)
      int lo = lbX(sBox, G, fminf(c0x0, c1x0) - maxSpan);
      int hi = lbX(sBox, G, fmaxf(c0x1p, c1x1p));
#pragma unroll 2
      for (int s = lo + wseg; s < hi; s += 4) {
        float4 gb = sBox[s];
        float2 mt = sMeta[s];
        uint32_t og = __float_as_uint(mt.y);
        am = min(am, packKey(c0x0, c0y0, c0x1p, c0y1p, car0, gb, mt.x, og));
        uint32_t p = packKey(c1x0, c1y0, c1x1p, c1y1p, car1, gb, mt.x, og);
        uint32_t hib = max(p, bk1);
        bk1 = min(bk1, p);
        bk2 = min(bk2, hib);
      }

#pragma unroll
      for (int m = 1; m <= 2; m <<= 1) {
        am = min(am, (uint32_t)__shfl_xor((int)am, m, 64));
        uint32_t q1 = (uint32_t)__shfl_xor((int)bk1, m, 64);
        uint32_t q2 = (uint32_t)__shfl_xor((int)bk2, m, 64);
        uint32_t hib = max(bk1, q1);
        bk1 = min(bk1, q1);
        bk2 = min(min(bk2, q2), hib);
      }

      if (wseg == 0) {
        int ai  = (int)(am  & 0x1FFu);  // ORIGINAL indices (reference semantics)
        int bi  = (int)(bk1 & 0x1FFu);
        int bi2 = (int)(bk2 & 0x1FFu);
        int sa = sO2S[ai];
        float4 ga4 = sBox[sa]; float aav = sMeta[sa].x;
        float aval = (aav < 1e29f) ? iouExact(c0x0, c0y0, c0x1, c0y1, car0, ga4, aav) : 0.0f;
        int bIdx = (ai == bi) ? bi2 : bi;  // b with b[ai] zeroed, then argmax
        int sb = sO2S[bIdx];
        float4 gb4 = sBox[sb]; float abv = sMeta[sb].x;
        float bval = (abv < 1e29f) ? iouExact(c1x0, c1y0, c1x1, c1y1, car1, gb4, abv) : 0.0f;
        sRes[sList[slot]] = make_float2(aval, bval);
      }
    }
  }
  __syncthreads();

  // ---- IoU L1 loss (owner lane reads phase-2 result) ----
  if (needy) {   // implies seg==0 && i<A
    float2 r = sRes[q];
    if (fg0) t_iou += fabsf(riv0 - r.x);
    if (fg1) t_iou += fabsf(riv1 - fmaxf(r.y, 0.0f));
  }

  // block reduction: wave shuffle -> LDS -> one private record per block.
  // NO global atomics (same-line device-scope atomics serialized at ~114 us).
  float vals[7] = {t_cls, t_bbox, t_iou, t_num, t_npos, t_nfg, t_ncnt};
  int lane = threadIdx.x & 63;
  int wid = threadIdx.x >> 6;
#pragma unroll
  for (int k = 0; k < 7; ++k) {
    float s = waveSum(vals[k]);
    if (lane == 0) sRed[wid][k] = s;
  }
  __syncthreads();
  if (threadIdx.x < 7) {
    double s = (double)sRed[0][threadIdx.x] + (double)sRed[1][threadIdx.x] +
               (double)sRed[2][threadIdx.x] + (double)sRed[3][threadIdx.x];
    size_t bid = (size_t)blockIdx.y * gridDim.x + blockIdx.x;
    partial[bid * 8 + threadIdx.x] = s;    // 64-B record, no contention
  }
}

// Third dispatch on the same stream: kernel-boundary ordering makes the
// partial records visible. Sums nB x 7 doubles (~240 KB, L2-resident).
__global__ __launch_bounds__(1024) void retina_finalize(
    const double* __restrict__ partial, int nB, float* __restrict__ out) {
  __shared__ double sRed[16][7];
  double loc[7] = {0.0, 0.0, 0.0, 0.0, 0.0, 0.0, 0.0};
  for (int b = threadIdx.x; b < nB; b += 1024) {
    const double* r = partial + (size_t)b * 8;
#pragma unroll
    for (int k = 0; k < 7; ++k) loc[k] += r[k];
  }
  int lane = threadIdx.x & 63;
  int wid = threadIdx.x >> 6;
#pragma unroll
  for (int k = 0; k < 7; ++k) {
    double v = loc[k];
#pragma unroll
    for (int o = 32; o > 0; o >>= 1) v += __shfl_down(v, o, 64);
    if (lane == 0) sRed[wid][k] = v;
  }
  __syncthreads();
  if (threadIdx.x == 0) {
    double t[7];
#pragma unroll
    for (int k = 0; k < 7; ++k) {
      double s = 0.0;
      for (int w = 0; w < 16; ++w) s += sRed[w][k];
      t[k] = s;
    }
    double dpos = t[4] > 1.0 ? t[4] : 1.0;
    double dfg  = t[5] > 1.0 ? t[5] : 1.0;
    double dcnt = t[6] > 1.0 ? t[6] : 1.0;
    out[0] = (float)(t[0] / dpos);
    out[1] = (float)(2.0 * t[1] / dfg);
    out[2] = (float)(2.0 * t[2] / dfg);
    out[3] = (float)(t[3] / dcnt);
  }
}

extern "C" void kernel_launch(void* const* d_in, const int* in_sizes, int n_in,
                              void* d_out, int out_size, void* d_ws, size_t ws_size,
                              hipStream_t stream) {
  const float* pred_cls = (const float*)d_in[0];
  const float* rpn_num  = (const float*)d_in[1];
  const float* pred_reg = (const float*)d_in[2];
  const float* anchors  = (const float*)d_in[3];
  const float* rpn_iou  = (const float*)d_in[4];
  const float* boxes    = (const float*)d_in[5];
  // d_in[6] = im_info: unused by the reference math

  int A = in_sizes[3] / 4;
  int n = in_sizes[0] / (2 * A);
  int G = in_sizes[5] / (5 * n);

  char* ws = (char*)d_ws;
  char* sorted = ws;                                          // n * 16 KB
  double* partial = (double*)(ws + (size_t)n * IMG_WS_STRIDE);

  gt_sort<<<dim3(n, 1, 1), dim3(256, 1, 1), 0, stream>>>(boxes, G, sorted);

  int nBx = (A + 63) / 64;   // 64 anchors per block
  int nB = nBx * n;
  dim3 grid(nBx, n, 1);
  retina_main<<<grid, dim3(256, 1, 1), 0, stream>>>(
      pred_cls, rpn_num, pred_reg, anchors, rpn_iou,
      A, G, sorted, partial);
  retina_finalize<<<dim3(1, 1, 1), dim3(1024, 1, 1), 0, stream>>>(
      partial, nB, (float*)d_out);
}